// Round 4
// baseline (1675.992 us; speedup 1.0000x reference)
//
#include <hip/hip_runtime.h>

// Problem constants (fixed by the reference)
#define NN 50000
#define EE 1600000
#define FIN 512
#define HH 128

#define PART_NODES 64
#define P 782               // ceil(50000/64)
#define B_BLOCKS 256
#define CHUNK 6250          // EE / B_BLOCKS exactly

typedef short s16x8 __attribute__((ext_vector_type(8)));
typedef float f32x4 __attribute__((ext_vector_type(4)));

static __device__ inline unsigned short f2bf(float f) {
    // fp32 -> bf16 bits, round-to-nearest-even
    unsigned u = __float_as_uint(f);
    unsigned r = (u + 0x7fffu + ((u >> 16) & 1u)) >> 16;
    return (unsigned short)r;
}

// ---------------- build: histogram -> scan -> deterministic scatter ----------------
// No per-edge global atomics anywhere (they cost ~64B HBM write each on gfx950).

__global__ __launch_bounds__(256) void hist_kernel(const int* __restrict__ dst,
                                                   int* __restrict__ blockHist) {
    __shared__ int hist[P];
    for (int i = threadIdx.x; i < P; i += 256) hist[i] = 0;
    __syncthreads();
    int base = blockIdx.x * CHUNK;
    for (int i = threadIdx.x; i < CHUNK; i += 256)
        atomicAdd(&hist[dst[base + i] >> 6], 1);
    __syncthreads();
    for (int i = threadIdx.x; i < P; i += 256)
        blockHist[blockIdx.x * P + i] = hist[i];
}

// one block per partition: exclusive scan down the block axis (in place), emit column total
__global__ __launch_bounds__(256) void scan_col(int* __restrict__ blockHist,
                                                int* __restrict__ colTotal) {
    int p = blockIdx.x;
    __shared__ int buf[256];
    int v = blockHist[threadIdx.x * P + p];
    buf[threadIdx.x] = v;
    __syncthreads();
    for (int off = 1; off < 256; off <<= 1) {
        int t = (threadIdx.x >= (unsigned)off) ? buf[threadIdx.x - off] : 0;
        __syncthreads();
        buf[threadIdx.x] += t;
        __syncthreads();
    }
    blockHist[threadIdx.x * P + p] = buf[threadIdx.x] - v;   // exclusive
    if (threadIdx.x == 255) colTotal[p] = buf[255];
}

// single block: exclusive scan over partition totals -> partStart[0..P]
__global__ __launch_bounds__(1024) void scan_part(const int* __restrict__ colTotal,
                                                  int* __restrict__ partStart) {
    __shared__ int buf[1024];
    int v = (threadIdx.x < P) ? colTotal[threadIdx.x] : 0;
    buf[threadIdx.x] = v;
    __syncthreads();
    for (int off = 1; off < 1024; off <<= 1) {
        int t = (threadIdx.x >= (unsigned)off) ? buf[threadIdx.x - off] : 0;
        __syncthreads();
        buf[threadIdx.x] += t;
        __syncthreads();
    }
    if (threadIdx.x < P) partStart[threadIdx.x] = buf[threadIdx.x] - v;
    if (threadIdx.x == P - 1) partStart[P] = buf[threadIdx.x];
}

// deterministic scatter: pos = partStart[p] + blockOff[b][p] + intra-block rank (LDS cursor)
__global__ __launch_bounds__(256) void scatter_binned(const int* __restrict__ src,
                                                      const int* __restrict__ dst,
                                                      const float* __restrict__ w,
                                                      const int* __restrict__ blockOff,
                                                      const int* __restrict__ partStart,
                                                      int2* __restrict__ binned) {
    __shared__ int cur[P];
    for (int i = threadIdx.x; i < P; i += 256) cur[i] = 0;
    __syncthreads();
    int b = blockIdx.x;
    int base = b * CHUNK;
    for (int i = threadIdx.x; i < CHUNK; i += 256) {
        int e = base + i;
        int s = src[e], d = dst[e];
        float we = w[e];
        int p = d >> 6;
        int rank = atomicAdd(&cur[p], 1);
        int pos = partStart[p] + blockOff[b * P + p] + rank;
        binned[pos] = make_int2(s | ((d & 63) << 16), __float_as_int(we));
    }
}

// dinv per node from binned records: deg = 1 + sum(w into node); dinv = rsqrt(deg)
__global__ __launch_bounds__(256) void dinv_kernel(const int2* __restrict__ binned,
                                                   const int* __restrict__ partStart,
                                                   float* __restrict__ dinv) {
    int p = blockIdx.x;
    __shared__ float degAcc[PART_NODES];
    if (threadIdx.x < PART_NODES) degAcc[threadIdx.x] = 0.0f;
    __syncthreads();
    int s0 = partStart[p], s1 = partStart[p + 1];
    for (int j = s0 + (int)threadIdx.x; j < s1; j += 256) {
        int2 r = binned[j];
        atomicAdd(&degAcc[r.x >> 16], __int_as_float(r.y));
    }
    __syncthreads();
    if (threadIdx.x < PART_NODES) {
        int node = p * PART_NODES + (int)threadIdx.x;
        if (node < NN) dinv[node] = rsqrtf(1.0f + degAcc[threadIdx.x]);
    }
}

// ---------------- GEMM1: h2[M,128](bf16) = dinv .* (x[M,512](f32) @ Wc[512,128](f32)) ----
// 256 threads = 4 waves in 2x2; tile 128x128; BK=32; 16x16x32 bf16 MFMA, 4x4 frags/wave.

__global__ __launch_bounds__(256) void gemm1_kernel(const float* __restrict__ A,
                                                    const float* __restrict__ B,
                                                    const float* __restrict__ dinv,
                                                    unsigned short* __restrict__ h2,
                                                    int M) {
    __shared__ short As[128][40];   // [m][k], pad to 40 (80B rows)
    __shared__ short Bs[128][40];   // [n][k]
    const int bm = blockIdx.x * 128;
    const int tid = threadIdx.x;
    const int wave = tid >> 6, lane = tid & 63;
    const int wm = wave >> 1, wn = wave & 1;
    const int mlane = lane & 15, quad = lane >> 4;

    f32x4 acc[4][4];
#pragma unroll
    for (int i = 0; i < 4; ++i)
#pragma unroll
        for (int j = 0; j < 4; ++j) acc[i][j] = (f32x4){0.f, 0.f, 0.f, 0.f};

    for (int k0 = 0; k0 < FIN; k0 += 32) {
#pragma unroll
        for (int i = 0; i < 4; ++i) {
            int task = tid + i * 256;
            int row = task >> 3, kq = task & 7;
            int grow = bm + row;
            float4 v = make_float4(0.f, 0.f, 0.f, 0.f);
            if (grow < M) v = *(const float4*)(A + (size_t)grow * FIN + k0 + kq * 4);
            ushort4 b;
            b.x = f2bf(v.x); b.y = f2bf(v.y); b.z = f2bf(v.z); b.w = f2bf(v.w);
            *(ushort4*)&As[row][kq * 4] = b;
        }
#pragma unroll
        for (int i = 0; i < 2; ++i) {
            int task = tid + i * 256;
            int n = task & 127, kg = task >> 7;
            unsigned short tmp[8];
#pragma unroll
            for (int j = 0; j < 8; ++j)
                tmp[j] = f2bf(B[(size_t)(k0 + kg * 8 + j) * HH + n]);
            *(s16x8*)&Bs[n][kg * 8] = *(s16x8*)tmp;
        }
        __syncthreads();

        s16x8 af[4], bfr[4];
#pragma unroll
        for (int mt = 0; mt < 4; ++mt)
            af[mt] = *(const s16x8*)&As[wm * 64 + mt * 16 + mlane][quad * 8];
#pragma unroll
        for (int nt = 0; nt < 4; ++nt)
            bfr[nt] = *(const s16x8*)&Bs[wn * 64 + nt * 16 + mlane][quad * 8];
#pragma unroll
        for (int mt = 0; mt < 4; ++mt)
#pragma unroll
            for (int nt = 0; nt < 4; ++nt)
                acc[mt][nt] = __builtin_amdgcn_mfma_f32_16x16x32_bf16(af[mt], bfr[nt], acc[mt][nt], 0, 0, 0);
        __syncthreads();
    }

#pragma unroll
    for (int mt = 0; mt < 4; ++mt) {
#pragma unroll
        for (int r = 0; r < 4; ++r) {
            int row = bm + wm * 64 + mt * 16 + quad * 4 + r;
            if (row < M) {
                float sc = dinv[row];
#pragma unroll
                for (int nt = 0; nt < 4; ++nt) {
                    int col = wn * 64 + nt * 16 + mlane;
                    h2[(size_t)row * HH + col] = f2bf(acc[mt][nt][r] * sc);
                }
            }
        }
    }
}

// ---------------- fused aggregation ----------------
// one block per partition (64 dst nodes); LDS fp32 accumulator [64][128] (32 KB).
// wave-per-edge: lane l handles packed feature pair (2l, 2l+1) of h2[src]; LDS atomic fma.
// agg[d] = bf16( b_conv + dinv[d] * (h2[d] + sum_e w_e * h2[src_e]) )

__global__ __launch_bounds__(256) void agg_fused(const unsigned int* __restrict__ h2u,
                                                 const int2* __restrict__ binned,
                                                 const int* __restrict__ partStart,
                                                 const float* __restrict__ dinv,
                                                 const float* __restrict__ b_conv,
                                                 unsigned int* __restrict__ aggu) {
    __shared__ float accum[PART_NODES][HH];
    const int p = blockIdx.x;
    const int tid = threadIdx.x;

    // init with self term h2[node]
#pragma unroll
    for (int i = 0; i < 16; ++i) {
        int task = tid + i * 256;        // 0..4095
        int nl = task >> 6, l = task & 63;
        int node = p * PART_NODES + nl;
        float v0 = 0.f, v1 = 0.f;
        if (node < NN) {
            unsigned u = h2u[(size_t)node * 64 + l];
            v0 = __uint_as_float(u << 16);
            v1 = __uint_as_float(u & 0xffff0000u);
        }
        accum[nl][2 * l]     = v0;
        accum[nl][2 * l + 1] = v1;
    }
    __syncthreads();

    const int s0 = partStart[p], s1 = partStart[p + 1];
    const int wave = tid >> 6, lane = tid & 63;
    int j = s0 + wave;
    for (; j + 4 < s1; j += 8) {
        int2 r0 = binned[j];
        int2 r1 = binned[j + 4];
        unsigned u0 = h2u[(size_t)(r0.x & 0xffff) * 64 + lane];
        unsigned u1 = h2u[(size_t)(r1.x & 0xffff) * 64 + lane];
        float w0 = __int_as_float(r0.y);
        float w1 = __int_as_float(r1.y);
        int d0 = r0.x >> 16, d1 = r1.x >> 16;
        atomicAdd(&accum[d0][2 * lane],     w0 * __uint_as_float(u0 << 16));
        atomicAdd(&accum[d0][2 * lane + 1], w0 * __uint_as_float(u0 & 0xffff0000u));
        atomicAdd(&accum[d1][2 * lane],     w1 * __uint_as_float(u1 << 16));
        atomicAdd(&accum[d1][2 * lane + 1], w1 * __uint_as_float(u1 & 0xffff0000u));
    }
    if (j < s1) {
        int2 r0 = binned[j];
        unsigned u0 = h2u[(size_t)(r0.x & 0xffff) * 64 + lane];
        float w0 = __int_as_float(r0.y);
        int d0 = r0.x >> 16;
        atomicAdd(&accum[d0][2 * lane],     w0 * __uint_as_float(u0 << 16));
        atomicAdd(&accum[d0][2 * lane + 1], w0 * __uint_as_float(u0 & 0xffff0000u));
    }
    __syncthreads();

    // epilogue: scale + bias + pack bf16
#pragma unroll
    for (int i = 0; i < 16; ++i) {
        int task = tid + i * 256;
        int nl = task >> 6, l = task & 63;
        int node = p * PART_NODES + nl;
        if (node < NN) {
            float di = dinv[node];
            float2 bc = ((const float2*)b_conv)[l];
            float v0 = bc.x + di * accum[nl][2 * l];
            float v1 = bc.y + di * accum[nl][2 * l + 1];
            aggu[(size_t)node * 64 + l] = (unsigned)f2bf(v0) | ((unsigned)f2bf(v1) << 16);
        }
    }
}

// ---------------- GEMM2: out[M,512](f32) = agg[M,128](bf16) @ Wl[128,512](f32) + b_lin ----

__global__ __launch_bounds__(256) void gemm2_kernel(const unsigned short* __restrict__ A,
                                                    const float* __restrict__ B,
                                                    const float* __restrict__ bias,
                                                    float* __restrict__ C,
                                                    int M) {
    __shared__ short As[128][40];
    __shared__ short Bs[128][40];
    const int bm = blockIdx.x * 128;
    const int bn = blockIdx.y * 128;
    const int tid = threadIdx.x;
    const int wave = tid >> 6, lane = tid & 63;
    const int wm = wave >> 1, wn = wave & 1;
    const int mlane = lane & 15, quad = lane >> 4;

    f32x4 acc[4][4];
#pragma unroll
    for (int i = 0; i < 4; ++i)
#pragma unroll
        for (int j = 0; j < 4; ++j) acc[i][j] = (f32x4){0.f, 0.f, 0.f, 0.f};

    for (int k0 = 0; k0 < HH; k0 += 32) {
#pragma unroll
        for (int i = 0; i < 2; ++i) {
            int task = tid + i * 256;
            int row = task >> 2, ch = task & 3;
            int grow = bm + row;
            s16x8 v = (s16x8){0, 0, 0, 0, 0, 0, 0, 0};
            if (grow < M) v = *(const s16x8*)(A + (size_t)grow * HH + k0 + ch * 8);
            *(s16x8*)&As[row][ch * 8] = v;
        }
#pragma unroll
        for (int i = 0; i < 2; ++i) {
            int task = tid + i * 256;
            int n = task & 127, kg = task >> 7;
            unsigned short tmp[8];
#pragma unroll
            for (int j = 0; j < 8; ++j)
                tmp[j] = f2bf(B[(size_t)(k0 + kg * 8 + j) * FIN + bn + n]);
            *(s16x8*)&Bs[n][kg * 8] = *(s16x8*)tmp;
        }
        __syncthreads();

        s16x8 af[4], bfr[4];
#pragma unroll
        for (int mt = 0; mt < 4; ++mt)
            af[mt] = *(const s16x8*)&As[wm * 64 + mt * 16 + mlane][quad * 8];
#pragma unroll
        for (int nt = 0; nt < 4; ++nt)
            bfr[nt] = *(const s16x8*)&Bs[wn * 64 + nt * 16 + mlane][quad * 8];
#pragma unroll
        for (int mt = 0; mt < 4; ++mt)
#pragma unroll
            for (int nt = 0; nt < 4; ++nt)
                acc[mt][nt] = __builtin_amdgcn_mfma_f32_16x16x32_bf16(af[mt], bfr[nt], acc[mt][nt], 0, 0, 0);
        __syncthreads();
    }

#pragma unroll
    for (int mt = 0; mt < 4; ++mt) {
#pragma unroll
        for (int r = 0; r < 4; ++r) {
            int row = bm + wm * 64 + mt * 16 + quad * 4 + r;
            if (row < M) {
#pragma unroll
                for (int nt = 0; nt < 4; ++nt) {
                    int col = bn + wn * 64 + nt * 16 + mlane;
                    C[(size_t)row * FIN + col] = acc[mt][nt][r] + bias[col];
                }
            }
        }
    }
}

// ---------------- launch ----------------

extern "C" void kernel_launch(void* const* d_in, const int* in_sizes, int n_in,
                              void* d_out, int out_size, void* d_ws, size_t ws_size,
                              hipStream_t stream) {
    const float* x      = (const float*)d_in[0];
    const int*   ei     = (const int*)d_in[1];
    const float* ew     = (const float*)d_in[2];
    const float* W_conv = (const float*)d_in[3];
    const float* b_conv = (const float*)d_in[4];
    const float* W_lin  = (const float*)d_in[5];
    const float* b_lin  = (const float*)d_in[6];
    float* out = (float*)d_out;

    const int* src = ei;
    const int* dst = ei + EE;

    // workspace layout (bytes, 256-aligned):
    char* ws = (char*)d_ws;
    int*            blockOff  = (int*)           (ws + 0);          //   800,768 (hist -> offsets in place)
    int*            colTotal  = (int*)           (ws + 800768);     //     3,328
    int*            partStart = (int*)           (ws + 804096);     //     3,328 (P+1 ints)
    float*          dinv      = (float*)         (ws + 807424);     //   200,704
    int2*           binned    = (int2*)          (ws + 1008128);    // 12,800,000
    unsigned short* h2        = (unsigned short*)(ws + 13808128);   // 12,800,000
    unsigned short* agg       = (unsigned short*)(ws + 26608128);   // 12,800,000
    // end: 39,408,128 bytes

    hist_kernel<<<B_BLOCKS, 256, 0, stream>>>(dst, blockOff);
    scan_col<<<P, 256, 0, stream>>>(blockOff, colTotal);
    scan_part<<<1, 1024, 0, stream>>>(colTotal, partStart);
    scatter_binned<<<B_BLOCKS, 256, 0, stream>>>(src, dst, ew, blockOff, partStart, binned);
    dinv_kernel<<<P, 256, 0, stream>>>(binned, partStart, dinv);

    // GEMM1: h2 = bf16(dinv .* (x @ W_conv))
    gemm1_kernel<<<dim3((NN + 127) / 128, 1), 256, 0, stream>>>(x, W_conv, dinv, h2, NN);

    // fused aggregation (bf16 -> bf16, LDS fp32 accumulate)
    agg_fused<<<P, 256, 0, stream>>>((const unsigned int*)h2, binned, partStart, dinv, b_conv,
                                     (unsigned int*)agg);

    // GEMM2: out = agg @ W_lin + b_lin
    gemm2_kernel<<<dim3((NN + 127) / 128, FIN / 128), 256, 0, stream>>>(agg, W_lin, b_lin, out, NN);
}